// Round 8
// baseline (78.102 us; speedup 1.0000x reference)
//
#include <hip/hip_runtime.h>

// LengthRegulator fused: x (B=32, C=384, T=1024) f32, duration (B,T) i32 in [0,8),
// max_len = 7168. One block per (batch, 8-channel group). Build the FULL
// 7168-frame frame->token map ONCE in LDS as u16 (14 KB, sentinel 0xFFFF for
// frames past mel_len), 2 barriers total, hoist all 28 token ids per thread
// into registers, then one dense barrier-free burst of 56 nontemporal f32x4
// stores (+ predicated L1-hot gathers). nt stores are mandatory (R6: plain
// stores trigger L2 write-allocate, +352 MB HBM reads).
// out0 = gathered x (zero past mel_len); out1 = mel_len as f32.

#define B_ 32
#define C_ 384
#define T_ 1024
#define MAXLEN_ 7168
#define FT_ 7                     // frame tiles of 1024 (7*1024 = 7168)
#define CPB_ 8                    // channels per block (32 KB x slab, L1)
#define NT_ 256                   // threads per block
#define NCG_ (C_ / CPB_)          // 48 channel groups
#define NWG_ (B_ * NCG_)          // 1536 blocks, divisible by 8
#define NXCD_ 8

typedef float f32x4 __attribute__((ext_vector_type(4)));

__global__ __launch_bounds__(NT_) void lr_fused_kernel(
    const int* __restrict__ dur,     // (B, T)
    const float* __restrict__ x,     // (B, C, T)
    float* __restrict__ out,         // (B, C, MAXLEN)
    float* __restrict__ mel_out)     // (B,) stored as float
{
    const int tid = threadIdx.x;

    // XCD-chunked bijective swizzle (T1)
    const int bid  = blockIdx.x;
    const int wgid = (bid & (NXCD_ - 1)) * (NWG_ / NXCD_) + (bid >> 3);
    const int cblk = wgid % NCG_;
    const int b    = wgid / NCG_;

    __shared__ unsigned short s_tok[MAXLEN_];   // 14336 B frame->token map
    __shared__ int s_w[NT_ / 64];               // per-wave scan totals

    // ---- init map to 0xFFFF: 896 int4 writes ----
    {
        const int4 f = make_int4(-1, -1, -1, -1);
        int4* m4 = (int4*)s_tok;
        m4[tid]       = f;
        m4[tid + 256] = f;
        m4[tid + 512] = f;
        if (tid < 128) m4[tid + 768] = f;
    }

    // ---- each thread loads 4 consecutive durations (coalesced int4) ----
    const int4 d4 = ((const int4*)(dur + b * T_))[tid];
    const int sum4 = d4.x + d4.y + d4.z + d4.w;

    // ---- inclusive scan of per-thread sums: wave shuffle + LDS cross-wave ----
    const int lane = tid & 63;
    const int wave = tid >> 6;
    int sc = sum4;
    #pragma unroll
    for (int d = 1; d < 64; d <<= 1) {
        int n = __shfl_up(sc, d, 64);
        if (lane >= d) sc += n;
    }
    if (lane == 63) s_w[wave] = sc;
    __syncthreads();                 // barrier 1: map init + s_w visible

    int woff = 0;
    #pragma unroll
    for (int w = 0; w < NT_ / 64; ++w)
        woff += (w < wave) ? s_w[w] : 0;
    const int mel = s_w[0] + s_w[1] + s_w[2] + s_w[3];

    if (cblk == 0 && tid == 0)
        mel_out[b] = (float)mel;

    // ---- scatter this thread's 4 tokens into the full map (u16 writes) ----
    {
        const int st = woff + sc - sum4;    // exclusive start
        const int base_tok = tid << 2;
        const int s0 = st;
        const int s1 = s0 + d4.x;
        const int s2 = s1 + d4.y;
        const int s3 = s2 + d4.z;
        const int starts[4] = { s0, s1, s2, s3 };
        const int lens[4]   = { d4.x, d4.y, d4.z, d4.w };
        #pragma unroll
        for (int k = 0; k < 4; ++k)
            for (int p = 0; p < lens[k]; ++p)
                s_tok[starts[k] + p] = (unsigned short)(base_tok + k);
    }
    __syncthreads();                 // barrier 2: map complete

    // ---- hoist all 28 token ids (7 tiles x 4 frames) into registers ----
    unsigned int tk[FT_][2];
    #pragma unroll
    for (int ft = 0; ft < FT_; ++ft) {
        const uint2 u = ((const uint2*)(s_tok + (ft << 10)))[tid];  // 8B read
        tk[ft][0] = u.x;
        tk[ft][1] = u.y;
    }

    const float* xb  = x   + ((size_t)b * C_ + cblk * CPB_) * T_;
    float*       ob0 = out + ((size_t)b * C_ + cblk * CPB_) * MAXLEN_ + (tid << 2);

    // ---- dense barrier-free store burst: 8 channels x 7 tiles ----
    #pragma unroll 2
    for (int cc = 0; cc < CPB_; ++cc) {
        const float* __restrict__ xr = xb + cc * T_;   // L1-hot 4 KB row
        float* obc = ob0 + (size_t)cc * MAXLEN_;
        #pragma unroll
        for (int ft = 0; ft < FT_; ++ft) {
            const unsigned int lo = tk[ft][0];
            const unsigned int hi = tk[ft][1];
            const unsigned int t0 = lo & 0xFFFFu, t1 = lo >> 16;
            const unsigned int t2 = hi & 0xFFFFu, t3 = hi >> 16;
            // always-in-bounds load (t & 1023) + branchless select
            const float a0 = xr[t0 & 1023u];
            const float a1 = xr[t1 & 1023u];
            const float a2 = xr[t2 & 1023u];
            const float a3 = xr[t3 & 1023u];
            f32x4 v;
            v.x = (t0 <= 1023u) ? a0 : 0.0f;
            v.y = (t1 <= 1023u) ? a1 : 0.0f;
            v.z = (t2 <= 1023u) ? a2 : 0.0f;
            v.w = (t3 <= 1023u) ? a3 : 0.0f;
            __builtin_nontemporal_store(v, (f32x4*)(obc + (ft << 10)));
        }
    }
}

extern "C" void kernel_launch(void* const* d_in, const int* in_sizes, int n_in,
                              void* d_out, int out_size, void* d_ws, size_t ws_size,
                              hipStream_t stream) {
    const float* x   = (const float*)d_in[0];
    const int*   dur = (const int*)d_in[1];
    // d_in[2] = max_len scalar (7168), compile-time constant here.

    float* out = (float*)d_out;
    float* mel_out = out + (size_t)B_ * C_ * MAXLEN_;  // 32 floats at the tail

    lr_fused_kernel<<<NWG_, NT_, 0, stream>>>(dur, x, out, mel_out);
}

// Round 9
// 67.383 us; speedup vs baseline: 1.1591x; 1.1591x over previous
//
#include <hip/hip_runtime.h>

// LengthRegulator fused: x (B=32, C=384, T=1024) f32, duration (B,T) i32 in [0,8),
// max_len = 7168. Block = (frame tile, 4-channel group, batch), 1D grid + XCD
// swizzle. R9 change: gathers moved OFF the TA/L1 pipe -> stage the 4 x rows
// into LDS with coalesced dwordx4 loads, gather via ds_read (separate pipe),
// so the nontemporal store stream owns the TA pipe. u16 token map in LDS.
// nt stores mandatory (R6: plain stores -> L2 write-allocate, +352 MB reads).
// CPB=4 keeps LDS at 18.2 KB -> 8 blocks/CU -> full 32-wave occupancy.
// out0 = gathered x (zero past mel_len); out1 = mel_len as f32.

#define B_ 32
#define C_ 384
#define T_ 1024
#define MAXLEN_ 7168
#define FT_ 7                     // frame tiles of 1024
#define CPB_ 4                    // channels per block
#define NT_ 256                   // threads per block
#define NCG_ (C_ / CPB_)          // 96 channel groups
#define NWG_ (FT_ * NCG_ * B_)    // 21504, divisible by 8
#define NXCD_ 8

typedef float f32x4 __attribute__((ext_vector_type(4)));

__global__ __launch_bounds__(NT_) void lr_fused_kernel(
    const int* __restrict__ dur,     // (B, T)
    const float* __restrict__ x,     // (B, C, T)
    float* __restrict__ out,         // (B, C, MAXLEN)
    float* __restrict__ mel_out)     // (B,) stored as float
{
    const int tid = threadIdx.x;

    // XCD-chunked bijective swizzle (T1)
    const int bid  = blockIdx.x;
    const int wgid = (bid & (NXCD_ - 1)) * (NWG_ / NXCD_) + (bid >> 3);
    const int ftile = wgid % FT_;
    const int rest  = wgid / FT_;
    const int cblk  = rest % NCG_;
    const int b     = rest / NCG_;
    const int f0    = ftile << 10;

    __shared__ float s_x[CPB_][T_];            // 16 KB staged x rows
    __shared__ unsigned short s_map[1024];     // 2 KB frame->token map (u16)
    __shared__ int s_w[NT_ / 64];

    // ---- dur load + wave-shuffle scan (as R5) ----
    const int4 d4 = ((const int4*)(dur + b * T_))[tid];
    const int sum4 = d4.x + d4.y + d4.z + d4.w;

    const int lane = tid & 63;
    const int wave = tid >> 6;
    int sc = sum4;
    #pragma unroll
    for (int d = 1; d < 64; d <<= 1) {
        int n = __shfl_up(sc, d, 64);
        if (lane >= d) sc += n;
    }
    if (lane == 63) s_w[wave] = sc;

    // init token map to 0xFFFF (sentinel -> zero output)
    ((int2*)s_map)[tid] = make_int2(-1, -1);
    __syncthreads();                            // barrier 1

    int woff = 0;
    #pragma unroll
    for (int w = 0; w < NT_ / 64; ++w)
        woff += (w < wave) ? s_w[w] : 0;
    const int mel = s_w[0] + s_w[1] + s_w[2] + s_w[3];

    if (ftile == 0 && cblk == 0 && tid == 0)
        mel_out[b] = (float)mel;

    float* ob = out + ((size_t)b * C_ + cblk * CPB_) * MAXLEN_ + f0 + (tid << 2);

    // ---- block-uniform early exit: dead tile -> zeros, no staging reads ----
    if (f0 >= mel) {
        const f32x4 z = {0.0f, 0.0f, 0.0f, 0.0f};
        #pragma unroll
        for (int cc = 0; cc < CPB_; ++cc)
            __builtin_nontemporal_store(z, (f32x4*)(ob + (size_t)cc * MAXLEN_));
        return;
    }

    // ---- stage 4 x rows into LDS: 4 coalesced dwordx4 loads per thread ----
    const float* xb = x + ((size_t)b * C_ + cblk * CPB_) * T_;
    #pragma unroll
    for (int r = 0; r < CPB_; ++r)
        ((f32x4*)s_x[r])[tid] = ((const f32x4*)(xb + r * T_))[tid];

    // ---- scatter this thread's 4 tokens into the tile map ----
    {
        const int st = woff + sc - sum4;        // exclusive start
        const int base_tok = tid << 2;
        const int s0 = st;
        const int s1 = s0 + d4.x;
        const int s2 = s1 + d4.y;
        const int s3 = s2 + d4.z;
        const int starts[4] = { s0, s1, s2, s3 };
        const int lens[4]   = { d4.x, d4.y, d4.z, d4.w };
        #pragma unroll
        for (int k = 0; k < 4; ++k) {
            int lo = starts[k] - f0;
            int hi = lo + lens[k];
            lo = lo < 0 ? 0 : lo;
            hi = hi > 1024 ? 1024 : hi;
            for (int p = lo; p < hi; ++p)
                s_map[p] = (unsigned short)(base_tok + k);
        }
    }
    __syncthreads();                            // barrier 2: staging + map done

    // ---- gather from LDS (ds pipe), nt-store burst (TA pipe) ----
    const uint2 m = ((const uint2*)s_map)[tid]; // tokens for frames tid*4..+3
    const unsigned int t0 = m.x & 0xFFFFu, t1 = m.x >> 16;
    const unsigned int t2 = m.y & 0xFFFFu, t3 = m.y >> 16;

    #pragma unroll
    for (int cc = 0; cc < CPB_; ++cc) {
        const float a0 = s_x[cc][t0 & 1023u];
        const float a1 = s_x[cc][t1 & 1023u];
        const float a2 = s_x[cc][t2 & 1023u];
        const float a3 = s_x[cc][t3 & 1023u];
        f32x4 v;
        v.x = (t0 <= 1023u) ? a0 : 0.0f;
        v.y = (t1 <= 1023u) ? a1 : 0.0f;
        v.z = (t2 <= 1023u) ? a2 : 0.0f;
        v.w = (t3 <= 1023u) ? a3 : 0.0f;
        __builtin_nontemporal_store(v, (f32x4*)(ob + (size_t)cc * MAXLEN_));
    }
}

extern "C" void kernel_launch(void* const* d_in, const int* in_sizes, int n_in,
                              void* d_out, int out_size, void* d_ws, size_t ws_size,
                              hipStream_t stream) {
    const float* x   = (const float*)d_in[0];
    const int*   dur = (const int*)d_in[1];
    // d_in[2] = max_len scalar (7168), compile-time constant here.

    float* out = (float*)d_out;
    float* mel_out = out + (size_t)B_ * C_ * MAXLEN_;  // 32 floats at the tail

    lr_fused_kernel<<<NWG_, NT_, 0, stream>>>(dur, x, out, mel_out);
}